// Round 1
// baseline (466.539 us; speedup 1.0000x reference)
//
#include <hip/hip_runtime.h>

typedef __bf16 bf16_t;
typedef bf16_t bf16x8 __attribute__((ext_vector_type(8)));
typedef float f32x4 __attribute__((ext_vector_type(4)));
typedef unsigned short u16x8_t __attribute__((ext_vector_type(8)));

#define NHEADS 8
#define TOTTOK 49152
#define HD 64
#define QBLK 128
#define KVB 64

__device__ __forceinline__ unsigned short f2b(float f) {
    bf16_t h = (bf16_t)f;
    return __builtin_bit_cast(unsigned short, h);
}
__device__ __forceinline__ bf16x8 asbf(u16x8_t u) { return __builtin_bit_cast(bf16x8, u); }

__global__ __launch_bounds__(256, 2)
void flash_attn_kernel(const float* __restrict__ Q, const float* __restrict__ K,
                       const float* __restrict__ V, float* __restrict__ O)
{
    // K tile: [key][d], padded row 72 (2-way bank conflicts only)
    __shared__ unsigned short Ks[KVB][72];
    // V tile transposed: [d][key], padded row 72
    __shared__ unsigned short Vt[HD][72];
    // P per wave per stripe: [row][key]
    __shared__ unsigned short Ps[4][2][16][72];

    const int bid = blockIdx.x;
    int Slen, bl2, off, qtl2, base;
    if (bid < 1024)      { Slen = 2048; bl2 = 3; off = 32768; qtl2 = 4; base = 0;    }
    else if (bid < 2048) { Slen = 1024; bl2 = 4; off = 16384; qtl2 = 3; base = 1024; }
    else                 { Slen = 512;  bl2 = 5; off = 0;     qtl2 = 2; base = 2048; }
    const int r  = bid - base;
    const int p  = r >> qtl2;                  // (head, seq) problem id
    const int qt = r & ((1 << qtl2) - 1);      // q-tile within sequence
    const int h  = p >> bl2;
    const int j  = p & ((1 << bl2) - 1);

    const size_t seqbase = ((size_t)h * TOTTOK + (size_t)off + (size_t)j * Slen) * HD;
    const float* Qb = Q + seqbase + (size_t)(qt * QBLK) * HD;
    const float* Kb = K + seqbase;
    const float* Vb = V + seqbase;
    float*       Ob = O + seqbase + (size_t)(qt * QBLK) * HD;

    const int tid  = threadIdx.x;
    const int wave = tid >> 6;
    const int lane = tid & 63;
    const int lg   = lane >> 4;   // 16-lane group 0..3
    const int li   = lane & 15;

    const float SC = 0.125f * 1.4426950408889634f;  // 1/sqrt(64) * log2(e)

    // ---- Q fragments, hi/lo split (fp32-accurate QK^T) ----
    bf16x8 qhi[2][2], qlo[2][2];
#pragma unroll
    for (int st = 0; st < 2; ++st)
#pragma unroll
      for (int c = 0; c < 2; ++c) {
        const float* src = Qb + (size_t)(wave*32 + st*16 + li) * HD + c*32 + lg*8;
        float4 a = *(const float4*)src;
        float4 b = *(const float4*)(src + 4);
        float f[8] = {a.x,a.y,a.z,a.w,b.x,b.y,b.z,b.w};
        bf16x8 hi, lo;
#pragma unroll
        for (int i = 0; i < 8; ++i) {
          float sf = f[i] * SC;
          bf16_t hh = (bf16_t)sf;
          hi[i] = hh;
          lo[i] = (bf16_t)(sf - (float)hh);
        }
        qhi[st][c] = hi; qlo[st][c] = lo;
      }

    f32x4 oacc[2][4];
    f32x4 lacc[2];
    float mrow[2][4];
#pragma unroll
    for (int st = 0; st < 2; ++st) {
      lacc[st] = (f32x4){0.f,0.f,0.f,0.f};
#pragma unroll
      for (int t = 0; t < 4; ++t) oacc[st][t] = (f32x4){0.f,0.f,0.f,0.f};
#pragma unroll
      for (int rr = 0; rr < 4; ++rr) mrow[st][rr] = -1e30f;
    }

    bf16x8 ones;
#pragma unroll
    for (int i = 0; i < 8; ++i) ones[i] = (bf16_t)1.0f;

    // staging lane mappings
    const int kkey0 = tid >> 4;          // K: key rows kkey0 + {0,16,32,48}
    const int kd    = (tid & 15) * 4;    // K: d chunk (coalesced along d)
    const int vkey  = tid & 63;          // V: one key per lane (conflict-free LDS-T write)
    const int vd0   = (tid >> 6) * 16;   // V: 16 consecutive d per thread

    const int niter = Slen >> 6;
    for (int it = 0; it < niter; ++it) {
      const float* Ksrc = Kb + (size_t)(it * KVB) * HD;
      const float* Vsrc = Vb + (size_t)(it * KVB) * HD;

      // stage K (row-major bf16)
#pragma unroll
      for (int i = 0; i < 4; ++i) {
        int key = kkey0 + i*16;
        float4 kv = *(const float4*)(Ksrc + (size_t)key*HD + kd);
        ushort4 u;
        u.x = f2b(kv.x); u.y = f2b(kv.y); u.z = f2b(kv.z); u.w = f2b(kv.w);
        *(ushort4*)&Ks[key][kd] = u;
      }
      // stage V transposed ([d][key])
#pragma unroll
      for (int i = 0; i < 4; ++i) {
        int d = vd0 + i*4;
        float4 vv = *(const float4*)(Vsrc + (size_t)vkey*HD + d);
        Vt[d+0][vkey] = f2b(vv.x);
        Vt[d+1][vkey] = f2b(vv.y);
        Vt[d+2][vkey] = f2b(vv.z);
        Vt[d+3][vkey] = f2b(vv.w);
      }
      __syncthreads();   // barrier A: staging visible

      // fragment loads (all Ks/Vt reads happen here)
      u16x8_t kf[4][2], vf[2][4];
#pragma unroll
      for (int kt = 0; kt < 4; ++kt)
#pragma unroll
        for (int c = 0; c < 2; ++c)
          kf[kt][c] = *(const u16x8_t*)&Ks[kt*16 + li][c*32 + lg*8];
#pragma unroll
      for (int c = 0; c < 2; ++c)
#pragma unroll
        for (int t = 0; t < 4; ++t)
          vf[c][t] = *(const u16x8_t*)&Vt[t*16 + li][c*32 + lg*8];
      __syncthreads();   // barrier B: frees Ks/Vt for next iteration's staging

      // QK^T + online softmax + P write (per stripe)
#pragma unroll
      for (int st = 0; st < 2; ++st) {
        f32x4 s[4];
#pragma unroll
        for (int kt = 0; kt < 4; ++kt) {
          f32x4 z = (f32x4){0.f,0.f,0.f,0.f};
          z = __builtin_amdgcn_mfma_f32_16x16x32_bf16(qhi[st][0], asbf(kf[kt][0]), z, 0, 0, 0);
          z = __builtin_amdgcn_mfma_f32_16x16x32_bf16(qlo[st][0], asbf(kf[kt][0]), z, 0, 0, 0);
          z = __builtin_amdgcn_mfma_f32_16x16x32_bf16(qhi[st][1], asbf(kf[kt][1]), z, 0, 0, 0);
          z = __builtin_amdgcn_mfma_f32_16x16x32_bf16(qlo[st][1], asbf(kf[kt][1]), z, 0, 0, 0);
          s[kt] = z;
        }
#pragma unroll
        for (int rr = 0; rr < 4; ++rr) {
          float mx = fmaxf(fmaxf(s[0][rr], s[1][rr]), fmaxf(s[2][rr], s[3][rr]));
          mx = fmaxf(mx, __shfl_xor(mx, 1));
          mx = fmaxf(mx, __shfl_xor(mx, 2));
          mx = fmaxf(mx, __shfl_xor(mx, 4));
          mx = fmaxf(mx, __shfl_xor(mx, 8));
          float mold = mrow[st][rr];
          float mnew = fmaxf(mold, mx);
          float corr = exp2f(mold - mnew);
          mrow[st][rr] = mnew;
          lacc[st][rr] *= corr;
#pragma unroll
          for (int t = 0; t < 4; ++t) oacc[st][t][rr] *= corr;
          int row = lg*4 + rr;
#pragma unroll
          for (int kt = 0; kt < 4; ++kt) {
            float pv = exp2f(s[kt][rr] - mnew);
            Ps[wave][st][row][kt*16 + li] = f2b(pv);
          }
        }
      }

      // PV (P read is same-wave: in-order DS, no barrier needed)
#pragma unroll
      for (int st = 0; st < 2; ++st) {
#pragma unroll
        for (int c = 0; c < 2; ++c) {
          u16x8_t pa = *(const u16x8_t*)&Ps[wave][st][li][c*32 + lg*8];
          bf16x8 pab = asbf(pa);
          lacc[st] = __builtin_amdgcn_mfma_f32_16x16x32_bf16(pab, ones, lacc[st], 0, 0, 0);
#pragma unroll
          for (int t = 0; t < 4; ++t)
            oacc[st][t] = __builtin_amdgcn_mfma_f32_16x16x32_bf16(pab, asbf(vf[c][t]), oacc[st][t], 0, 0, 0);
        }
      }
    }

    // epilogue: O = acc / l  (l computed through identical bf16 P -> error cancels)
#pragma unroll
    for (int st = 0; st < 2; ++st) {
#pragma unroll
      for (int rr = 0; rr < 4; ++rr) {
        float inv = 1.0f / lacc[st][rr];
        int row = wave*32 + st*16 + lg*4 + rr;
        float* dst = Ob + (size_t)row * HD;
#pragma unroll
        for (int t = 0; t < 4; ++t)
          dst[t*16 + li] = oacc[st][t][rr] * inv;
      }
    }
}

extern "C" void kernel_launch(void* const* d_in, const int* in_sizes, int n_in,
                              void* d_out, int out_size, void* d_ws, size_t ws_size,
                              hipStream_t stream) {
    (void)in_sizes; (void)n_in; (void)out_size; (void)d_ws; (void)ws_size;
    const float* Q = (const float*)d_in[0];
    const float* K = (const float*)d_in[1];
    const float* V = (const float*)d_in[2];
    float* O = (float*)d_out;
    flash_attn_kernel<<<dim3(3072), dim3(256), 0, stream>>>(Q, K, V, O);
}

// Round 2
// 460.058 us; speedup vs baseline: 1.0141x; 1.0141x over previous
//
#include <hip/hip_runtime.h>

typedef __bf16 bf16_t;
typedef bf16_t bf16x8 __attribute__((ext_vector_type(8)));
typedef float f32x4 __attribute__((ext_vector_type(4)));
typedef unsigned short u16x8_t __attribute__((ext_vector_type(8)));

#define NHEADS 8
#define TOTTOK 49152
#define HD 64
#define QBLK 128
#define KVB 64

__device__ __forceinline__ unsigned short f2b(float f) {
    bf16_t h = (bf16_t)f;
    return __builtin_bit_cast(unsigned short, h);
}
__device__ __forceinline__ bf16x8 asbf(u16x8_t u) { return __builtin_bit_cast(bf16x8, u); }

__global__ __launch_bounds__(256, 3)
void flash_attn_kernel(const float* __restrict__ Q, const float* __restrict__ K,
                       const float* __restrict__ V, float* __restrict__ O)
{
    // double-buffered K (row-major [key][d]) and V-transposed ([d][key]); pad 72
    __shared__ unsigned short Ks[2][KVB][72];
    __shared__ unsigned short Vt[2][HD][72];
    // P per wave, reused across stripes (same-wave in-order DS)
    __shared__ unsigned short Ps[4][16][72];

    const int bid = blockIdx.x;
    int Slen, bl2, off, qtl2, base;
    if (bid < 1024)      { Slen = 2048; bl2 = 3; off = 32768; qtl2 = 4; base = 0;    }
    else if (bid < 2048) { Slen = 1024; bl2 = 4; off = 16384; qtl2 = 3; base = 1024; }
    else                 { Slen = 512;  bl2 = 5; off = 0;     qtl2 = 2; base = 2048; }
    // XCD-chunked swizzle: q-tiles of one sequence -> one XCD; segments
    // interleaved across XCDs for load balance. xcd = launched%8.
    const int l    = bid - base;
    const int xcd  = l & 7;
    const int slot = l >> 3;
    const int p    = xcd + ((slot >> qtl2) << 3);
    const int qt   = slot & ((1 << qtl2) - 1);
    const int h    = p >> bl2;
    const int j    = p & ((1 << bl2) - 1);

    const size_t seqbase = ((size_t)h * TOTTOK + (size_t)off + (size_t)j * Slen) * HD;
    const float* Qb = Q + seqbase + (size_t)(qt * QBLK) * HD;
    const float* Kb = K + seqbase;
    const float* Vb = V + seqbase;
    float*       Ob = O + seqbase + (size_t)(qt * QBLK) * HD;

    const int tid  = threadIdx.x;
    const int wave = tid >> 6;
    const int lane = tid & 63;
    const int lg   = lane >> 4;   // 16-lane group 0..3
    const int li   = lane & 15;

    const float SC = 0.125f * 1.4426950408889634f;  // 1/sqrt(64) * log2(e)

    // ---- Q fragments, hi/lo split (fp32-accurate QK^T) ----
    bf16x8 qhi[2][2], qlo[2][2];
#pragma unroll
    for (int st = 0; st < 2; ++st)
#pragma unroll
      for (int c = 0; c < 2; ++c) {
        const float* src = Qb + (size_t)(wave*32 + st*16 + li) * HD + c*32 + lg*8;
        float4 a = *(const float4*)src;
        float4 b = *(const float4*)(src + 4);
        float f[8] = {a.x,a.y,a.z,a.w,b.x,b.y,b.z,b.w};
        bf16x8 hi, lo;
#pragma unroll
        for (int i = 0; i < 8; ++i) {
          float sf = f[i] * SC;
          bf16_t hh = (bf16_t)sf;
          hi[i] = hh;
          lo[i] = (bf16_t)(sf - (float)hh);
        }
        qhi[st][c] = hi; qlo[st][c] = lo;
      }

    f32x4 oacc[2][4];
    f32x4 lacc[2];
    float mrow[2][4];
#pragma unroll
    for (int st = 0; st < 2; ++st) {
      lacc[st] = (f32x4){0.f,0.f,0.f,0.f};
#pragma unroll
      for (int t = 0; t < 4; ++t) oacc[st][t] = (f32x4){0.f,0.f,0.f,0.f};
#pragma unroll
      for (int rr = 0; rr < 4; ++rr) mrow[st][rr] = -1e30f;
    }

    bf16x8 ones;
#pragma unroll
    for (int i = 0; i < 8; ++i) ones[i] = (bf16_t)1.0f;

    // staging lane mappings
    const int kkey = tid >> 4;           // K: key rows kkey + {0,16,32,48}
    const int kd   = (tid & 15) * 4;     // K: d chunk (coalesced along d)
    const int vkg  = (tid & 15) * 4;     // V: 4 keys vkg..vkg+3
    const int vdc  = (tid >> 4) * 4;     // V: 4 d's  vdc..vdc+3

    float4 kr[4], vr[4];
    auto LOADT = [&](int it) {
      const float* Ksrc = Kb + (size_t)(it * KVB) * HD;
      const float* Vsrc = Vb + (size_t)(it * KVB) * HD;
#pragma unroll
      for (int i = 0; i < 4; ++i)
        kr[i] = *(const float4*)(Ksrc + (size_t)(kkey + i*16)*HD + kd);
#pragma unroll
      for (int i = 0; i < 4; ++i)
        vr[i] = *(const float4*)(Vsrc + (size_t)(vkg + i)*HD + vdc);
    };
    auto STORET = [&](int buf) {
#pragma unroll
      for (int i = 0; i < 4; ++i) {
        ushort4 u;
        u.x = f2b(kr[i].x); u.y = f2b(kr[i].y); u.z = f2b(kr[i].z); u.w = f2b(kr[i].w);
        *(ushort4*)&Ks[buf][kkey + i*16][kd] = u;
      }
      float vm[4][4];
#pragma unroll
      for (int i = 0; i < 4; ++i) {
        vm[i][0] = vr[i].x; vm[i][1] = vr[i].y; vm[i][2] = vr[i].z; vm[i][3] = vr[i].w;
      }
#pragma unroll
      for (int jj = 0; jj < 4; ++jj) {
        ushort4 u;
        u.x = f2b(vm[0][jj]); u.y = f2b(vm[1][jj]); u.z = f2b(vm[2][jj]); u.w = f2b(vm[3][jj]);
        *(ushort4*)&Vt[buf][vdc + jj][vkg] = u;
      }
    };

    const int niter = Slen >> 6;

    // prologue: stage tile 0
    LOADT(0);
    STORET(0);
    __syncthreads();

    for (int it = 0; it < niter; ++it) {
      const int cur = it & 1;
      const bool more = (it + 1 < niter);
      if (more) LOADT(it + 1);   // async: latency hides under compute below

      // compute from buf[cur]
#pragma unroll
      for (int st = 0; st < 2; ++st) {
        f32x4 s[4];
#pragma unroll
        for (int kt = 0; kt < 4; ++kt) {
          // key-relabeled K fragment: tile kt covers keys {li*4+kt}
          u16x8_t k0 = *(const u16x8_t*)&Ks[cur][li*4 + kt][lg*8];
          u16x8_t k1 = *(const u16x8_t*)&Ks[cur][li*4 + kt][32 + lg*8];
          f32x4 z = (f32x4){0.f,0.f,0.f,0.f};
          z = __builtin_amdgcn_mfma_f32_16x16x32_bf16(qhi[st][0], asbf(k0), z, 0, 0, 0);
          z = __builtin_amdgcn_mfma_f32_16x16x32_bf16(qlo[st][0], asbf(k0), z, 0, 0, 0);
          z = __builtin_amdgcn_mfma_f32_16x16x32_bf16(qhi[st][1], asbf(k1), z, 0, 0, 0);
          z = __builtin_amdgcn_mfma_f32_16x16x32_bf16(qlo[st][1], asbf(k1), z, 0, 0, 0);
          s[kt] = z;
        }
#pragma unroll
        for (int rr = 0; rr < 4; ++rr) {
          float mx = fmaxf(fmaxf(s[0][rr], s[1][rr]), fmaxf(s[2][rr], s[3][rr]));
          mx = fmaxf(mx, __shfl_xor(mx, 1));
          mx = fmaxf(mx, __shfl_xor(mx, 2));
          mx = fmaxf(mx, __shfl_xor(mx, 4));
          mx = fmaxf(mx, __shfl_xor(mx, 8));
          float mold = mrow[st][rr];
          float mnew = fmaxf(mold, mx);
          float corr = __builtin_amdgcn_exp2f(mold - mnew);
          mrow[st][rr] = mnew;
          lacc[st][rr] *= corr;
#pragma unroll
          for (int t = 0; t < 4; ++t) oacc[st][t][rr] *= corr;
          // contiguous P store: cols li*4 .. li*4+3 = keys li*4+kt
          ushort4 pu;
          pu.x = f2b(__builtin_amdgcn_exp2f(s[0][rr] - mnew));
          pu.y = f2b(__builtin_amdgcn_exp2f(s[1][rr] - mnew));
          pu.z = f2b(__builtin_amdgcn_exp2f(s[2][rr] - mnew));
          pu.w = f2b(__builtin_amdgcn_exp2f(s[3][rr] - mnew));
          *(ushort4*)&Ps[wave][lg*4 + rr][li*4] = pu;
        }
        // PV (same-wave in-order DS: P read after P write needs no barrier)
#pragma unroll
        for (int c = 0; c < 2; ++c) {
          u16x8_t pa = *(const u16x8_t*)&Ps[wave][li][c*32 + lg*8];
          bf16x8 pab = asbf(pa);
          lacc[st] = __builtin_amdgcn_mfma_f32_16x16x32_bf16(pab, ones, lacc[st], 0, 0, 0);
#pragma unroll
          for (int t = 0; t < 4; ++t) {
            u16x8_t vfrag = *(const u16x8_t*)&Vt[cur][t*16 + li][c*32 + lg*8];
            oacc[st][t] = __builtin_amdgcn_mfma_f32_16x16x32_bf16(pab, asbf(vfrag), oacc[st][t], 0, 0, 0);
          }
        }
      }

      if (more) {
        STORET(cur ^ 1);      // write next tile into the other buffer
        __syncthreads();      // single barrier per iteration
      }
    }

    // epilogue: O = acc / l  (l computed through identical bf16 P -> error cancels)
#pragma unroll
    for (int st = 0; st < 2; ++st) {
#pragma unroll
      for (int rr = 0; rr < 4; ++rr) {
        float inv = 1.0f / lacc[st][rr];
        int row = wave*32 + st*16 + lg*4 + rr;
        float* dst = Ob + (size_t)row * HD;
#pragma unroll
        for (int t = 0; t < 4; ++t)
          dst[t*16 + li] = oacc[st][t][rr] * inv;
      }
    }
}

extern "C" void kernel_launch(void* const* d_in, const int* in_sizes, int n_in,
                              void* d_out, int out_size, void* d_ws, size_t ws_size,
                              hipStream_t stream) {
    (void)in_sizes; (void)n_in; (void)out_size; (void)d_ws; (void)ws_size;
    const float* Q = (const float*)d_in[0];
    const float* K = (const float*)d_in[1];
    const float* V = (const float*)d_in[2];
    float* O = (float*)d_out;
    flash_attn_kernel<<<dim3(3072), dim3(256), 0, stream>>>(Q, K, V, O);
}

// Round 3
// 240.892 us; speedup vs baseline: 1.9367x; 1.9098x over previous
//
#include <hip/hip_runtime.h>

typedef __bf16 bf16_t;
typedef bf16_t bf16x8 __attribute__((ext_vector_type(8)));
typedef float f32x4 __attribute__((ext_vector_type(4)));
typedef unsigned short u16x8_t __attribute__((ext_vector_type(8)));
typedef unsigned int u32x4_t __attribute__((ext_vector_type(4)));

#define HD 64
#define TOTTOK 49152
#define KVB 64

__device__ __forceinline__ unsigned short f2b(float f) {
    bf16_t h = (bf16_t)f;
    return __builtin_bit_cast(unsigned short, h);
}
__device__ __forceinline__ bf16x8 asbf(u16x8_t u) { return __builtin_bit_cast(bf16x8, u); }
__device__ __forceinline__ bf16x8 asbf4(u32x4_t u) { return __builtin_bit_cast(bf16x8, u); }

__global__ __launch_bounds__(256, 2)
void flash_attn_kernel(const float* __restrict__ Q, const float* __restrict__ K,
                       const float* __restrict__ V, float* __restrict__ O)
{
    // double-buffered K [key][d] and V^T [d][key], pad 72 (row-stride-1 reads -> 2-way free)
    __shared__ unsigned short Ks[2][KVB][72];
    __shared__ unsigned short Vt[2][HD][72];

    const int bid = blockIdx.x;
    int Slen, bl2, off, qtl2, base;
    if (bid < 1024)      { Slen = 2048; bl2 = 3; off = 32768; qtl2 = 4; base = 0;    }
    else if (bid < 2048) { Slen = 1024; bl2 = 4; off = 16384; qtl2 = 3; base = 1024; }
    else                 { Slen = 512;  bl2 = 5; off = 0;     qtl2 = 2; base = 2048; }
    const int l    = bid - base;
    const int xcd  = l & 7;
    const int slot = l >> 3;
    const int p    = xcd + ((slot >> qtl2) << 3);
    const int qt   = slot & ((1 << qtl2) - 1);
    const int hh   = p >> bl2;
    const int sj   = p & ((1 << bl2) - 1);

    const size_t seqbase = ((size_t)hh * TOTTOK + (size_t)off + (size_t)sj * Slen) * HD;
    const float* Qb = Q + seqbase + (size_t)(qt * 128) * HD;
    const float* Kb = K + seqbase;
    const float* Vb = V + seqbase;
    float*       Ob = O + seqbase + (size_t)(qt * 128) * HD;

    const int tid  = threadIdx.x;
    const int wave = tid >> 6;
    const int lane = tid & 63;
    const int lg   = lane >> 4;
    const int li   = lane & 15;
    const bool lam = (lg & 1) != 0;

    const float SC = 0.125f * 1.4426950408889634f;  // 1/sqrt(64) * log2(e)

    // ---- Q fragments hi/lo (B-operand: n=li=query, k=c*32+lg*8+i) ----
    bf16x8 qhi[2][2], qlo[2][2];
#pragma unroll
    for (int st = 0; st < 2; ++st)
#pragma unroll
      for (int c = 0; c < 2; ++c) {
        const float* src = Qb + (size_t)(wave*32 + st*16 + li) * HD + c*32 + lg*8;
        float4 a = *(const float4*)src;
        float4 b = *(const float4*)(src + 4);
        float f[8] = {a.x,a.y,a.z,a.w,b.x,b.y,b.z,b.w};
        bf16x8 hi, lo;
#pragma unroll
        for (int i = 0; i < 8; ++i) {
          float sf = f[i] * SC;
          bf16_t hb = (bf16_t)sf;
          hi[i] = hb;
          lo[i] = (bf16_t)(sf - (float)hb);
        }
        qhi[st][c] = hi; qlo[st][c] = lo;
      }

    f32x4 oacc[2][4];   // O^T[d=16t+4lg+rr][q=li]
    f32x4 laccf[2];     // l[q=li] via ones-MFMA (all regs equal)
    float mrow[2] = {-1e30f, -1e30f};
#pragma unroll
    for (int st = 0; st < 2; ++st) {
      laccf[st] = (f32x4){0.f,0.f,0.f,0.f};
#pragma unroll
      for (int t = 0; t < 4; ++t) oacc[st][t] = (f32x4){0.f,0.f,0.f,0.f};
    }

    u16x8_t onesu;
#pragma unroll
    for (int i = 0; i < 8; ++i) onesu[i] = 0x3F80;  // bf16 1.0
    const bf16x8 ones = asbf(onesu);

    // staging lane mappings
    const int kkey = tid >> 4;
    const int kd   = (tid & 15) * 4;
    const int vkg  = (tid & 15) * 4;
    const int vdc  = (tid >> 4) * 4;

    float4 kr[4], vr[4];
    auto LOADT = [&](int it) {
      const float* Ksrc = Kb + (size_t)(it * KVB) * HD;
      const float* Vsrc = Vb + (size_t)(it * KVB) * HD;
#pragma unroll
      for (int i = 0; i < 4; ++i)
        kr[i] = *(const float4*)(Ksrc + (size_t)(kkey + i*16)*HD + kd);
#pragma unroll
      for (int i = 0; i < 4; ++i)
        vr[i] = *(const float4*)(Vsrc + (size_t)(vkg + i)*HD + vdc);
    };
    auto STORET = [&](int buf) {
#pragma unroll
      for (int i = 0; i < 4; ++i) {
        ushort4 u;
        u.x = f2b(kr[i].x); u.y = f2b(kr[i].y); u.z = f2b(kr[i].z); u.w = f2b(kr[i].w);
        *(ushort4*)&Ks[buf][kkey + i*16][kd] = u;
      }
      float vm[4][4];
#pragma unroll
      for (int i = 0; i < 4; ++i) {
        vm[i][0] = vr[i].x; vm[i][1] = vr[i].y; vm[i][2] = vr[i].z; vm[i][3] = vr[i].w;
      }
#pragma unroll
      for (int jj = 0; jj < 4; ++jj) {
        ushort4 u;
        u.x = f2b(vm[0][jj]); u.y = f2b(vm[1][jj]); u.z = f2b(vm[2][jj]); u.w = f2b(vm[3][jj]);
        *(ushort4*)&Vt[buf][vdc + jj][vkg] = u;
      }
    };

    const int niter = Slen >> 6;
    LOADT(0);
    STORET(0);
    __syncthreads();

    for (int it = 0; it < niter; ++it) {
      const int cur = it & 1;
      const bool more = (it + 1 < niter);
      if (more) LOADT(it + 1);   // T14: issue early, write after compute

      // ---- QK^T swapped (A=K, B=Q): S^T[key][q], K-frags read once per iter
      f32x4 s[2][4];
      __builtin_amdgcn_s_setprio(1);
#pragma unroll
      for (int kt = 0; kt < 4; ++kt) {
        u16x8_t k0 = *(const u16x8_t*)&Ks[cur][kt*16 + li][lg*8];
        u16x8_t k1 = *(const u16x8_t*)&Ks[cur][kt*16 + li][32 + lg*8];
        bf16x8 kb0 = asbf(k0), kb1 = asbf(k1);
#pragma unroll
        for (int st = 0; st < 2; ++st) {
          f32x4 z = (f32x4){0.f,0.f,0.f,0.f};
          z = __builtin_amdgcn_mfma_f32_16x16x32_bf16(kb0, qhi[st][0], z, 0, 0, 0);
          z = __builtin_amdgcn_mfma_f32_16x16x32_bf16(kb0, qlo[st][0], z, 0, 0, 0);
          z = __builtin_amdgcn_mfma_f32_16x16x32_bf16(kb1, qhi[st][1], z, 0, 0, 0);
          z = __builtin_amdgcn_mfma_f32_16x16x32_bf16(kb1, qlo[st][1], z, 0, 0, 0);
          s[st][kt] = z;
        }
      }
      __builtin_amdgcn_s_setprio(0);

      // ---- defer-max softmax + in-register P->B-fragment exchange
      unsigned int pf[2][2][4];
#pragma unroll
      for (int st = 0; st < 2; ++st) {
        float p01 = fmaxf(fmaxf(s[st][0][0], s[st][0][1]), fmaxf(s[st][0][2], s[st][0][3]));
        float p23 = fmaxf(fmaxf(s[st][1][0], s[st][1][1]), fmaxf(s[st][1][2], s[st][1][3]));
        float p45 = fmaxf(fmaxf(s[st][2][0], s[st][2][1]), fmaxf(s[st][2][2], s[st][2][3]));
        float p67 = fmaxf(fmaxf(s[st][3][0], s[st][3][1]), fmaxf(s[st][3][2], s[st][3][3]));
        float pmax = fmaxf(fmaxf(p01, p23), fmaxf(p45, p67));
        if (!__all(pmax <= mrow[st] + 8.0f)) {   // T13: rarely taken after iter 0
          float mx = pmax;
          mx = fmaxf(mx, __shfl_xor(mx, 16));
          mx = fmaxf(mx, __shfl_xor(mx, 32));
          float mnew = fmaxf(mrow[st], mx);
          float corr = __builtin_amdgcn_exp2f(mrow[st] - mnew);
          mrow[st] = mnew;
          laccf[st] *= corr;
#pragma unroll
          for (int t = 0; t < 4; ++t) oacc[st][t] *= corr;
        }
        const float m = mrow[st];
        unsigned int W[4][2];   // W[kt][j]: packed bf16 pair, keys 16kt+4lg+{2j,2j+1}, q=li
#pragma unroll
        for (int kt = 0; kt < 4; ++kt) {
#pragma unroll
          for (int jw = 0; jw < 2; ++jw) {
            float e0 = __builtin_amdgcn_exp2f(s[st][kt][2*jw]   - m);
            float e1 = __builtin_amdgcn_exp2f(s[st][kt][2*jw+1] - m);
            W[kt][jw] = (unsigned int)f2b(e0) | ((unsigned int)f2b(e1) << 16);
          }
        }
        // exchange: word m of B-frag(c) = W[2c+h][m&1] from lane (2*lam+(m>>1))*16+li.
        // permlane32_swap handles the h (kt) selection via register-half swap;
        // ds_swizzle xor16 handles the within-32 group hop; lam selects.
#pragma unroll
        for (int c = 0; c < 2; ++c) {
          unsigned int a0 = W[2*c][0], b0 = W[2*c+1][0];
          unsigned int a1 = W[2*c][1], b1 = W[2*c+1][1];
          asm("v_permlane32_swap_b32 %0, %1" : "+v"(a0), "+v"(b0));
          asm("v_permlane32_swap_b32 %0, %1" : "+v"(a1), "+v"(b1));
          unsigned int sa0 = __builtin_amdgcn_ds_swizzle((int)a0, 0x401F);
          unsigned int sb0 = __builtin_amdgcn_ds_swizzle((int)b0, 0x401F);
          unsigned int sa1 = __builtin_amdgcn_ds_swizzle((int)a1, 0x401F);
          unsigned int sb1 = __builtin_amdgcn_ds_swizzle((int)b1, 0x401F);
          pf[st][c][0] = lam ? sb0 : a0;
          pf[st][c][1] = lam ? sb1 : a1;
          pf[st][c][2] = lam ? b0  : sa0;
          pf[st][c][3] = lam ? b1  : sa1;
        }
      }

      // ---- PV: O^T = V^T . P^T (A=V^T frag, B=P frag); l via ones-MFMA
      __builtin_amdgcn_s_setprio(1);
#pragma unroll
      for (int c = 0; c < 2; ++c) {
        u32x4_t pw0 = {pf[0][c][0], pf[0][c][1], pf[0][c][2], pf[0][c][3]};
        u32x4_t pw1 = {pf[1][c][0], pf[1][c][1], pf[1][c][2], pf[1][c][3]};
        bf16x8 pb0 = asbf4(pw0), pb1 = asbf4(pw1);
        laccf[0] = __builtin_amdgcn_mfma_f32_16x16x32_bf16(ones, pb0, laccf[0], 0, 0, 0);
        laccf[1] = __builtin_amdgcn_mfma_f32_16x16x32_bf16(ones, pb1, laccf[1], 0, 0, 0);
#pragma unroll
        for (int t = 0; t < 4; ++t) {
          u16x8_t vf = *(const u16x8_t*)&Vt[cur][t*16 + li][c*32 + lg*8];
          bf16x8 vb = asbf(vf);
          oacc[0][t] = __builtin_amdgcn_mfma_f32_16x16x32_bf16(vb, pb0, oacc[0][t], 0, 0, 0);
          oacc[1][t] = __builtin_amdgcn_mfma_f32_16x16x32_bf16(vb, pb1, oacc[1][t], 0, 0, 0);
        }
      }
      __builtin_amdgcn_s_setprio(0);

      if (more) {
        STORET(cur ^ 1);
        __syncthreads();
      }
    }

    // ---- epilogue: lane holds O^T[d=16t+4lg+rr][q=li]; divide by l, store float4
#pragma unroll
    for (int st = 0; st < 2; ++st) {
      float inv = 1.0f / laccf[st][0];
      float* dst = Ob + (size_t)(wave*32 + st*16 + li) * HD + lg*4;
#pragma unroll
      for (int t = 0; t < 4; ++t) {
        float4 o4;
        o4.x = oacc[st][t][0] * inv;
        o4.y = oacc[st][t][1] * inv;
        o4.z = oacc[st][t][2] * inv;
        o4.w = oacc[st][t][3] * inv;
        *(float4*)(dst + t*16) = o4;
      }
    }
}

extern "C" void kernel_launch(void* const* d_in, const int* in_sizes, int n_in,
                              void* d_out, int out_size, void* d_ws, size_t ws_size,
                              hipStream_t stream) {
    (void)in_sizes; (void)n_in; (void)out_size; (void)d_ws; (void)ws_size;
    const float* Q = (const float*)d_in[0];
    const float* K = (const float*)d_in[1];
    const float* V = (const float*)d_in[2];
    float* O = (float*)d_out;
    flash_attn_kernel<<<dim3(3072), dim3(256), 0, stream>>>(Q, K, V, O);
}

// Round 4
// 220.875 us; speedup vs baseline: 2.1122x; 1.0906x over previous
//
#include <hip/hip_runtime.h>

typedef __bf16 bf16_t;
typedef bf16_t bf16x8 __attribute__((ext_vector_type(8)));
typedef float f32x4 __attribute__((ext_vector_type(4)));
typedef unsigned short u16x8_t __attribute__((ext_vector_type(8)));
typedef unsigned int u32x4_t __attribute__((ext_vector_type(4)));

#define HD 64
#define TOTTOK 49152

__device__ __forceinline__ unsigned short f2b(float f) {
    bf16_t h = (bf16_t)f;
    return __builtin_bit_cast(unsigned short, h);
}
__device__ __forceinline__ bf16x8 asbf(u16x8_t u) { return __builtin_bit_cast(bf16x8, u); }
__device__ __forceinline__ bf16x8 asbf4(u32x4_t u) { return __builtin_bit_cast(bf16x8, u); }

__global__ __launch_bounds__(256, 2)
void flash_attn_kernel(const float* __restrict__ Q, const float* __restrict__ K,
                       const float* __restrict__ V, float* __restrict__ O)
{
    // fragment-major LDS: [buf][chunk][lane][8 shorts]; frag read = base + lane*16
    // + chunk*1024 (immediate) -> lane-linear ds_read_b128, conflict-free.
    // K: chunk = kt*2+c, lane=lg*16+li holds K[kt*16+li][c*32+lg*8 .. +8)
    // V: chunk = t*2+c,  lane       holds V^T[t*16+li][c*32+lg*8 .. +8)
    __shared__ unsigned short Kf[2][8][64][8];
    __shared__ unsigned short Vf[2][8][64][8];

    const int bid = blockIdx.x;
    int Slen, bl2, off, qtl2, base;
    if (bid < 512)       { Slen = 2048; bl2 = 3; off = 32768; qtl2 = 3; base = 0;    }
    else if (bid < 1024) { Slen = 1024; bl2 = 4; off = 16384; qtl2 = 2; base = 512;  }
    else                 { Slen = 512;  bl2 = 5; off = 0;     qtl2 = 1; base = 1024; }
    const int l    = bid - base;
    const int xcd  = l & 7;
    const int slot = l >> 3;
    const int p    = xcd + ((slot >> qtl2) << 3);
    const int qt   = slot & ((1 << qtl2) - 1);
    const int hh   = p >> bl2;
    const int sj   = p & ((1 << bl2) - 1);

    const size_t seqbase = ((size_t)hh * TOTTOK + (size_t)off + (size_t)sj * Slen) * HD;
    const float* Qb = Q + seqbase + (size_t)(qt * 256) * HD;
    const float* Kb = K + seqbase;
    const float* Vb = V + seqbase;
    float*       Ob = O + seqbase + (size_t)(qt * 256) * HD;

    const int tid  = threadIdx.x;
    const int wave = tid >> 6;
    const int lane = tid & 63;
    const int lg   = lane >> 4;
    const int li   = lane & 15;
    const bool lam = (lg & 1) != 0;

    const float SC = 0.125f * 1.4426950408889634f;  // 1/sqrt(64) * log2(e)

    // ---- Q fragments (B-operand: n=li=query, k=c*32+lg*8+i), 64 q/wave ----
    bf16x8 qh[4][2];
#pragma unroll
    for (int st = 0; st < 4; ++st)
#pragma unroll
      for (int c = 0; c < 2; ++c) {
        const float* src = Qb + (size_t)(wave*64 + st*16 + li) * HD + c*32 + lg*8;
        float4 a = *(const float4*)src;
        float4 b = *(const float4*)(src + 4);
        float f[8] = {a.x,a.y,a.z,a.w,b.x,b.y,b.z,b.w};
        bf16x8 hi;
#pragma unroll
        for (int i = 0; i < 8; ++i) hi[i] = (bf16_t)(f[i] * SC);
        qh[st][c] = hi;
      }

    f32x4 oacc[4][4];     // O^T[d=16t+4lg+rr][q=li], stripe st
    float lsum[4];        // per-lane partial sum of P (rescaled online)
    float mrow[4];
#pragma unroll
    for (int st = 0; st < 4; ++st) {
      lsum[st] = 0.f; mrow[st] = -1e30f;
#pragma unroll
      for (int t = 0; t < 4; ++t) oacc[st][t] = (f32x4){0.f,0.f,0.f,0.f};
    }

    // ---- staging maps (256 threads, 64x64 fp32 tile each for K and V) ----
    const int kkey = tid >> 4;            // K row within 16-group
    const int kd   = (tid & 15) * 4;      // K col (4 floats)
    const int kch  = (kd >> 5);           // c of dest chunk
    const int klan = kkey + ((kd >> 3) & 3) * 16;
    const int kel  = kd & 7;              // 0 or 4
    const int vkg  = (tid & 15) * 4;      // V rows vkg..vkg+3
    const int vdc  = (tid >> 4) * 4;      // V cols vdc..vdc+3
    const int vch  = (vdc >> 4) * 2 + (vkg >> 5);
    const int vlan = ((vkg >> 3) & 3) * 16 + (vdc & 15);
    const int vel  = vkg & 7;

    float4 kr[4], vr[4];
    auto LOADT = [&](int it) {
      const float* Ksrc = Kb + (size_t)(it * 64) * HD;
      const float* Vsrc = Vb + (size_t)(it * 64) * HD;
#pragma unroll
      for (int i = 0; i < 4; ++i)
        kr[i] = *(const float4*)(Ksrc + (size_t)(kkey + i*16)*HD + kd);
#pragma unroll
      for (int i = 0; i < 4; ++i)
        vr[i] = *(const float4*)(Vsrc + (size_t)(vkg + i)*HD + vdc);
    };
    auto STORET = [&](int buf) {
#pragma unroll
      for (int i = 0; i < 4; ++i) {
        ushort4 u;
        u.x = f2b(kr[i].x); u.y = f2b(kr[i].y); u.z = f2b(kr[i].z); u.w = f2b(kr[i].w);
        *(ushort4*)&Kf[buf][i*2 + kch][klan][kel] = u;
      }
      float vm[4][4];
#pragma unroll
      for (int i = 0; i < 4; ++i) {
        vm[i][0] = vr[i].x; vm[i][1] = vr[i].y; vm[i][2] = vr[i].z; vm[i][3] = vr[i].w;
      }
#pragma unroll
      for (int di = 0; di < 4; ++di) {
        ushort4 u;
        u.x = f2b(vm[0][di]); u.y = f2b(vm[1][di]); u.z = f2b(vm[2][di]); u.w = f2b(vm[3][di]);
        *(ushort4*)&Vf[buf][vch][vlan + di][vel] = u;
      }
    };

    const int niter = Slen >> 6;
    LOADT(0);
    STORET(0);
    __syncthreads();

    for (int it = 0; it < niter; ++it) {
      const int cur = it & 1;
      const bool more = (it + 1 < niter);
      if (more) LOADT(it + 1);   // T14: issue early, LDS-write after compute

      // K fragments, lane-linear reads, held across all stripes
      bf16x8 kf[4][2];
#pragma unroll
      for (int kt = 0; kt < 4; ++kt)
#pragma unroll
        for (int c = 0; c < 2; ++c)
          kf[kt][c] = asbf(*(const u16x8_t*)&Kf[cur][kt*2 + c][lane][0]);

      u32x4_t pb[4][2];
#pragma unroll
      for (int st = 0; st < 4; ++st) {
        // ---- QK^T swapped (A=K, B=Q): S^T[key][q]
        f32x4 s[4];
        __builtin_amdgcn_s_setprio(1);
#pragma unroll
        for (int kt = 0; kt < 4; ++kt) {
          f32x4 z = (f32x4){0.f,0.f,0.f,0.f};
          z = __builtin_amdgcn_mfma_f32_16x16x32_bf16(kf[kt][0], qh[st][0], z, 0, 0, 0);
          z = __builtin_amdgcn_mfma_f32_16x16x32_bf16(kf[kt][1], qh[st][1], z, 0, 0, 0);
          s[kt] = z;
        }
        __builtin_amdgcn_s_setprio(0);

        // ---- defer-max online softmax (T13)
        float p01 = fmaxf(fmaxf(s[0][0], s[0][1]), fmaxf(s[0][2], s[0][3]));
        float p23 = fmaxf(fmaxf(s[1][0], s[1][1]), fmaxf(s[1][2], s[1][3]));
        float p45 = fmaxf(fmaxf(s[2][0], s[2][1]), fmaxf(s[2][2], s[2][3]));
        float p67 = fmaxf(fmaxf(s[3][0], s[3][1]), fmaxf(s[3][2], s[3][3]));
        float pmax = fmaxf(fmaxf(p01, p23), fmaxf(p45, p67));
        if (!__all(pmax <= mrow[st] + 8.0f)) {
          float mx = pmax;
          mx = fmaxf(mx, __shfl_xor(mx, 16));
          mx = fmaxf(mx, __shfl_xor(mx, 32));
          float mnew = fmaxf(mrow[st], mx);
          float corr = __builtin_amdgcn_exp2f(mrow[st] - mnew);
          mrow[st] = mnew;
          lsum[st] *= corr;
#pragma unroll
          for (int t = 0; t < 4; ++t) oacc[st][t] *= corr;
        }
        const float m = mrow[st];
        unsigned int W[4][2];
        float ls = 0.f;
#pragma unroll
        for (int kt = 0; kt < 4; ++kt) {
#pragma unroll
          for (int jw = 0; jw < 2; ++jw) {
            float e0 = __builtin_amdgcn_exp2f(s[kt][2*jw]   - m);
            float e1 = __builtin_amdgcn_exp2f(s[kt][2*jw+1] - m);
            ls += e0 + e1;
            W[kt][jw] = (unsigned int)f2b(e0) | ((unsigned int)f2b(e1) << 16);
          }
        }
        lsum[st] += ls;

        // ---- in-register P -> B-fragment exchange (1 swizzle per word-pair)
#pragma unroll
        for (int c = 0; c < 2; ++c) {
          unsigned int a0 = W[2*c][0], b0 = W[2*c+1][0];
          unsigned int a1 = W[2*c][1], b1 = W[2*c+1][1];
          asm("v_permlane32_swap_b32 %0, %1" : "+v"(a0), "+v"(b0));
          asm("v_permlane32_swap_b32 %0, %1" : "+v"(a1), "+v"(b1));
          unsigned int q0 = lam ? a0 : b0;
          unsigned int q1 = lam ? a1 : b1;
          unsigned int s0 = __builtin_amdgcn_ds_swizzle((int)q0, 0x401F); // xor16
          unsigned int s1 = __builtin_amdgcn_ds_swizzle((int)q1, 0x401F);
          u32x4_t pw;
          pw[0] = lam ? s0 : a0;
          pw[1] = lam ? s1 : a1;
          pw[2] = lam ? b0 : s0;
          pw[3] = lam ? b1 : s1;
          pb[st][c] = pw;
        }
      }

      // ---- PV: O^T += V^T . P^T ; V frags read once, shared by all stripes
      __builtin_amdgcn_s_setprio(1);
#pragma unroll
      for (int c = 0; c < 2; ++c) {
#pragma unroll
        for (int t = 0; t < 4; ++t) {
          bf16x8 vb = asbf(*(const u16x8_t*)&Vf[cur][t*2 + c][lane][0]);
          oacc[0][t] = __builtin_amdgcn_mfma_f32_16x16x32_bf16(vb, asbf4(pb[0][c]), oacc[0][t], 0, 0, 0);
          oacc[1][t] = __builtin_amdgcn_mfma_f32_16x16x32_bf16(vb, asbf4(pb[1][c]), oacc[1][t], 0, 0, 0);
          oacc[2][t] = __builtin_amdgcn_mfma_f32_16x16x32_bf16(vb, asbf4(pb[2][c]), oacc[2][t], 0, 0, 0);
          oacc[3][t] = __builtin_amdgcn_mfma_f32_16x16x32_bf16(vb, asbf4(pb[3][c]), oacc[3][t], 0, 0, 0);
        }
      }
      __builtin_amdgcn_s_setprio(0);

      if (more) {
        STORET(cur ^ 1);
        __syncthreads();
      }
    }

    // ---- epilogue: finish l reduction across lg, divide, store
#pragma unroll
    for (int st = 0; st < 4; ++st) {
      float ls = lsum[st];
      ls += __shfl_xor(ls, 16);
      ls += __shfl_xor(ls, 32);
      float inv = 1.0f / ls;
      float* dst = Ob + (size_t)(wave*64 + st*16 + li) * HD + lg*4;
#pragma unroll
      for (int t = 0; t < 4; ++t) {
        float4 o4;
        o4.x = oacc[st][t][0] * inv;
        o4.y = oacc[st][t][1] * inv;
        o4.z = oacc[st][t][2] * inv;
        o4.w = oacc[st][t][3] * inv;
        *(float4*)(dst + t*16) = o4;
      }
    }
}

extern "C" void kernel_launch(void* const* d_in, const int* in_sizes, int n_in,
                              void* d_out, int out_size, void* d_ws, size_t ws_size,
                              hipStream_t stream) {
    (void)in_sizes; (void)n_in; (void)out_size; (void)d_ws; (void)ws_size;
    const float* Q = (const float*)d_in[0];
    const float* K = (const float*)d_in[1];
    const float* V = (const float*)d_in[2];
    float* O = (float*)d_out;
    flash_attn_kernel<<<dim3(1536), dim3(256), 0, stream>>>(Q, K, V, O);
}